// Round 14
// baseline (1494.903 us; speedup 1.0000x reference)
//
#include <hip/hip_runtime.h>
#include <math.h>

#define H_DIM 4096
#define NHEAD 32
#define HD 128
#define FF_DIM 14336

typedef unsigned short u16;
typedef __attribute__((ext_vector_type(8))) short bf16x8;
typedef __attribute__((ext_vector_type(4))) float f32x4;
typedef __attribute__((ext_vector_type(4))) unsigned short u16x4;

typedef const __attribute__((address_space(1))) void* gas_ptr;
typedef __attribute__((address_space(3))) void* las_ptr;

__device__ __forceinline__ void gload_lds16(const void* g, void* l) {
  __builtin_amdgcn_global_load_lds((gas_ptr)g, (las_ptr)l, 16, 0, 0);
}

__device__ __forceinline__ u16 f32_to_bf16(float f) {
  unsigned int u = __float_as_uint(f);
  u = (u + 0x7FFFu + ((u >> 16) & 1u)) >> 16;
  return (u16)u;
}
__device__ __forceinline__ float bf16_to_f32(u16 x) {
  return __uint_as_float(((unsigned int)x) << 16);
}

// read-once fp32 -> bf16 (non-temporal load keeps weight fp32 out of L2 so the
// following GEMM's bf16 panels stay resident — r10: -137us total)
__device__ __forceinline__ void conv4(const float* __restrict__ in,
                                      u16* __restrict__ out, long i) {
  const f32x4* p = reinterpret_cast<const f32x4*>(in) + i;
  f32x4 v = __builtin_nontemporal_load(p);
  u16x4 o;
  o.x = f32_to_bf16(v.x); o.y = f32_to_bf16(v.y);
  o.z = f32_to_bf16(v.z); o.w = f32_to_bf16(v.w);
  reinterpret_cast<u16x4*>(out)[i] = o;
}

// ---------------- fp32 -> bf16 weight conversion ----------------
__global__ void f2b_kernel(const float* __restrict__ in, u16* __restrict__ out, long n4) {
  long i = (long)blockIdx.x * blockDim.x + threadIdx.x;
  long stride = (long)gridDim.x * blockDim.x;
  for (; i < n4; i += stride) conv4(in, out, i);
}

// three equal-size weights -> one contiguous bf16 buffer
__global__ void f2b3_kernel(const float* __restrict__ a, const float* __restrict__ b,
                            const float* __restrict__ c, u16* __restrict__ out, long n4each) {
  long i = (long)blockIdx.x * blockDim.x + threadIdx.x;
  long st = (long)gridDim.x * blockDim.x;
  long tot = 3 * n4each;
  for (; i < tot; i += st) {
    const float* src; long j;
    if (i < n4each)            { src = a; j = i; }
    else if (i < 2 * n4each)   { src = b; j = i - n4each; }
    else                       { src = c; j = i - 2 * n4each; }
    const f32x4* p = reinterpret_cast<const f32x4*>(src) + j;
    f32x4 v = __builtin_nontemporal_load(p);
    u16x4 o;
    o.x = f32_to_bf16(v.x); o.y = f32_to_bf16(v.y);
    o.z = f32_to_bf16(v.z); o.w = f32_to_bf16(v.w);
    reinterpret_cast<u16x4*>(out)[i] = o;
  }
}

// ---------------- bias concat (fp32) ----------------
__global__ void bias_concat_kernel(const float* __restrict__ a, const float* __restrict__ b,
                                   const float* __restrict__ c, float* __restrict__ out) {
  int i = blockIdx.x * blockDim.x + threadIdx.x;
  float v;
  if (i < 4096) v = a[i];
  else if (i < 8192) v = b[i - 4096];
  else v = c[i - 8192];
  out[i] = v;
}

// ---------------- RMSNorm (fp32 in, bf16 out) ----------------
__global__ void rmsnorm_kernel(const float* __restrict__ in, const float* __restrict__ w,
                               u16* __restrict__ out) {
  int row = blockIdx.x;
  int tid = threadIdx.x;
  const float4* x4 = reinterpret_cast<const float4*>(in + (size_t)row * H_DIM);
  float4 vv[4];
  float ss = 0.f;
#pragma unroll
  for (int it = 0; it < 4; ++it) {
    float4 v = x4[tid + it * 256];
    vv[it] = v;
    ss += v.x * v.x + v.y * v.y + v.z * v.z + v.w * v.w;
  }
#pragma unroll
  for (int off = 1; off < 64; off <<= 1) ss += __shfl_xor(ss, off);
  __shared__ float part[4];
  if ((tid & 63) == 0) part[tid >> 6] = ss;
  __syncthreads();
  float tot = part[0] + part[1] + part[2] + part[3];
  float rinv = rsqrtf(tot * (1.0f / H_DIM) + 1e-6f);
  const float4* w4 = reinterpret_cast<const float4*>(w);
  u16* orow = out + (size_t)row * H_DIM;
#pragma unroll
  for (int it = 0; it < 4; ++it) {
    float4 v = vv[it];
    float4 wv = w4[tid + it * 256];
    ushort4 o;
    o.x = f32_to_bf16(v.x * rinv * wv.x);
    o.y = f32_to_bf16(v.y * rinv * wv.y);
    o.z = f32_to_bf16(v.z * rinv * wv.z);
    o.w = f32_to_bf16(v.w * rinv * wv.w);
    reinterpret_cast<ushort4*>(orow)[tid + it * 256] = o;
  }
}

// ================= 256x256 8-phase bf16 GEMM (T1+T2+T3+T4+T5) =================
// EXACT round-6 proven K-loop (288us FF, MfmaUtil 35.5%, 0 conflicts, VGPR 112).
// EPI_GLU: fused gate+up — block computes 256x128 of BOTH matrices over one
// A-tile. B-LDS rows 0-127 = wg cols (piece B1), 128-255 = wu cols (piece B2);
// piece split is by matrix so the row map is IDENTITY (each phase reads a whole
// half). acc[8][0..1]=gate, acc[8][2..3]=up; epilogue silu(g)*u -> tb only
// (kills the 59MB sg write + 59MB scattered re-read).
// Lessons ledger:
//  r5: unified VGPR budget 256/wave; reg-staged conversion pipelines spill.
//  r8: never co-schedule converter blocks with this kernel (L2 B-panel evict).
//  r9: frag-prefetch hoist NEUTRAL — compiler lgkmcnt already overlaps.
//  r10: nt-loads on read-once fp32 streams protect B-panel L2 residency.
enum { EPI_QKV = 0, EPI_O = 1, EPI_SILU = 2, EPI_MUL = 3, EPI_PART = 4, EPI_GLU = 5 };

template <int EPI, bool SPLIT>
__global__ __launch_bounds__(512, 2) void gemm256(
    const u16* __restrict__ A, const u16* __restrict__ B, const u16* __restrict__ Bu,
    void* __restrict__ outp, const float* __restrict__ bias, const void* __restrict__ extra,
    int M, int N, int K, int kLen) {
  __shared__ __align__(16) u16 As[2][256 * 64];
  __shared__ __align__(16) u16 Bs[2][256 * 64];
  const int tid = threadIdx.x;
  const int wid = tid >> 6, lane = tid & 63;
  const int lg = lane >> 4, li = lane & 15;
  const int wr = (wid >> 2) << 7;  // 0 / 128
  const int wc = (wid & 3) << 6;   // 0,64,128,192 (256-wide tiles)
  const int wcg = (wid & 3) << 5;  // 0,32,64,96  (GLU: 128-wide per matrix)

  const int nbm = M >> 8;
  const int nbn = (EPI == EPI_GLU) ? (N >> 7) : (N >> 8);
  const int nb = nbm * nbn;
  int wg = (blockIdx.x & 7) * (gridDim.x >> 3) + (blockIdx.x >> 3);
  int s = 0;
  if (SPLIT) { s = wg / nb; wg -= s * nb; }
  const int m0 = (wg % nbm) << 8;
  const int n0 = (EPI == EPI_GLU) ? ((wg / nbm) << 7) : ((wg / nbm) << 8);
  const int kB = SPLIT ? s * kLen : 0;
  const int NT = kLen >> 6;

  // staging source pointers (pre-inverse-swizzled) + LDS dest offsets
  const int r8 = tid >> 3;
  const int sl = ((tid & 7) ^ (r8 & 7)) << 3;
  const u16* sA[2][2];
  const u16* sB[2][2];
  int ldo[2][2];
#pragma unroll
  for (int P = 0; P < 2; ++P)
#pragma unroll
    for (int h = 0; h < 2; ++h) {
      int lr = P * 128 + h * 64 + r8;
      int ra = (lr & 63) | ((lr >> 1) & 64) | ((lr << 1) & 128);
      sA[P][h] = A + (size_t)(m0 + ra) * K + kB + sl;
      if (EPI == EPI_GLU) {
        const u16* srcm = P ? Bu : B;              // B1 half = wg, B2 half = wu
        sB[P][h] = srcm + (size_t)(n0 + h * 64 + r8) * K + sl;
      } else {
        int rb = (lr & 31) | ((lr & 96) << 1) | ((lr & 128) >> 2);
        sB[P][h] = B + (size_t)(n0 + rb) * K + kB + sl;
      }
      ldo[P][h] = (P * 128 + h * 64 + (wid << 3)) << 6;
    }

  auto stageA = [&](int P, int d, int ko) {
#pragma unroll
    for (int h = 0; h < 2; ++h)
      gload_lds16(sA[P][h] + ko, (void*)(&As[d][ldo[P][h]]));
  };
  auto stageB = [&](int P, int d, int ko) {
#pragma unroll
    for (int h = 0; h < 2; ++h)
      gload_lds16(sB[P][h] + ko, (void*)(&Bs[d][ldo[P][h]]));
  };

  bf16x8 a[4][2], b[4][2];
  f32x4 acc[8][4] = {};
  const int s20 = (lg ^ (li & 7)) << 3;
  const int s21 = ((4 + lg) ^ (li & 7)) << 3;

  auto ldA = [&](int d, int set) {
#pragma unroll
    for (int i = 0; i < 4; ++i) {
      int g = wr + set * 64 + i * 16;
      int lb = (g & 63) | ((g >> 1) & 64) | ((g << 1) & 128);
      const u16* base = &As[d][(lb + li) << 6];
      a[i][0] = *reinterpret_cast<const bf16x8*>(base + s20);
      a[i][1] = *reinterpret_cast<const bf16x8*>(base + s21);
    }
  };
  auto ldB = [&](int d, int set) {
#pragma unroll
    for (int jj = 0; jj < 2; ++jj) {
      int lb;
      if (EPI == EPI_GLU) {
        lb = set * 128 + wcg + jj * 16;            // identity map within half
      } else {
        int hh = wc + (set * 2 + jj) * 16;
        lb = ((hh & 32) << 2) | ((hh & 192) >> 1) | (hh & 31);
      }
      const u16* base = &Bs[d][(lb + li) << 6];
      b[set * 2 + jj][0] = *reinterpret_cast<const bf16x8*>(base + s20);
      b[set * 2 + jj][1] = *reinterpret_cast<const bf16x8*>(base + s21);
    }
  };
  auto mm = [&](int iset, int jset) {
    __builtin_amdgcn_s_setprio(1);
#pragma unroll
    for (int i = 0; i < 4; ++i)
#pragma unroll
      for (int jj = 0; jj < 2; ++jj)
#pragma unroll
        for (int kk = 0; kk < 2; ++kk)
          acc[iset * 4 + i][jset * 2 + jj] = __builtin_amdgcn_mfma_f32_16x16x32_bf16(
              a[i][kk], b[jset * 2 + jj][kk], acc[iset * 4 + i][jset * 2 + jj], 0, 0, 0);
    __builtin_amdgcn_s_setprio(0);
  };

  // prologue: stage tiles 0 and 1
  stageA(0, 0, 0); stageB(0, 0, 0); stageB(1, 0, 0); stageA(1, 0, 0);
  if (NT > 1) {
    stageA(0, 1, 64); stageB(0, 1, 64); stageB(1, 1, 64); stageA(1, 1, 64);
    asm volatile("s_waitcnt vmcnt(8)" ::: "memory");
  } else {
    asm volatile("s_waitcnt vmcnt(0)" ::: "memory");
  }
  __builtin_amdgcn_s_barrier();

  for (int t = 0; t < NT; ++t) {
    int d = t & 1;
    bool pf = (t + 2) < NT;
    int ko = (t + 2) << 6;
    // ---- phase 1: reads A1+B1; MFMA quadrant (i0-3, j0-1)
    ldB(d, 0); ldA(d, 0);
    __builtin_amdgcn_s_barrier();
    mm(0, 0);
    __builtin_amdgcn_s_barrier();
    // ---- phase 2: reads B2; stage t+2.{A1,B1}; MFMA (i0-3, j2-3)
    ldB(d, 1);
    if (pf) { stageA(0, d, ko); stageB(0, d, ko); }
    __builtin_amdgcn_s_barrier();
    mm(0, 1);
    __builtin_amdgcn_s_barrier();
    // ---- phase 3: reads A2; stage t+2.B2; MFMA (i4-7, j0-1)
    ldA(d, 1);
    if (pf) stageB(1, d, ko);
    __builtin_amdgcn_s_barrier();
    mm(1, 0);
    __builtin_amdgcn_s_barrier();
    // ---- phase 4: stage t+2.A2; counted vmcnt; MFMA (i4-7, j2-3)
    if (pf) {
      stageA(1, d, ko);
      asm volatile("s_waitcnt vmcnt(6)" ::: "memory");
    } else {
      asm volatile("s_waitcnt vmcnt(0)" ::: "memory");
    }
    __builtin_amdgcn_s_barrier();
    mm(1, 1);
    __builtin_amdgcn_s_barrier();
  }

  // ---- epilogue
  if (EPI == EPI_GLU) {
#pragma unroll
    for (int i = 0; i < 8; ++i) {
#pragma unroll
      for (int jj = 0; jj < 2; ++jj) {
        int col = n0 + wcg + jj * 16 + li;
#pragma unroll
        for (int r = 0; r < 4; ++r) {
          int row = m0 + wr + i * 16 + lg * 4 + r;
          float g = acc[i][jj][r];
          float u = acc[i][2 + jj][r];
          float sv = (g / (1.f + __expf(-g))) * u;
          ((u16*)outp)[(size_t)row * N + col] = f32_to_bf16(sv);
        }
      }
    }
    return;
  }
#pragma unroll
  for (int i = 0; i < 8; ++i) {
#pragma unroll
    for (int j = 0; j < 4; ++j) {
      int col = n0 + wc + j * 16 + li;
      float bv = 0.f;
      if (EPI == EPI_QKV || EPI == EPI_O) bv = bias[col];
      if (EPI == EPI_PART && bias != nullptr && s == 0) bv = bias[col];
#pragma unroll
      for (int r = 0; r < 4; ++r) {
        int row = m0 + wr + i * 16 + lg * 4 + r;
        float v = acc[i][j][r] + bv;
        size_t idx = (size_t)row * N + col;
        if (EPI == EPI_QKV) {
          ((u16*)outp)[idx] = f32_to_bf16(v);
        } else if (EPI == EPI_O) {
          const float* res = (const float*)extra;
          ((float*)outp)[idx] = res[idx] + v;
        } else if (EPI == EPI_SILU) {
          float sv = v / (1.f + __expf(-v));
          ((u16*)outp)[idx] = f32_to_bf16(sv);
        } else if (EPI == EPI_MUL) {
          const u16* sg = (const u16*)extra;
          ((u16*)outp)[idx] = f32_to_bf16(v * bf16_to_f32(sg[idx]));
        } else {  // EPI_PART: split-K partial, plain fp32 (bias folded at s==0)
          ((float*)outp)[(size_t)s * M * N + idx] = v;
        }
      }
    }
  }
}

// ---------------- split-K reduce + residual: out = res + p0 + p1 ----------------
__global__ void reduce_down(const float* __restrict__ p, const float* __restrict__ res,
                            float* __restrict__ out, long n4, long str4) {
  long i = (long)blockIdx.x * blockDim.x + threadIdx.x;
  long st = (long)gridDim.x * blockDim.x;
  for (; i < n4; i += st) {
    f32x4 h = reinterpret_cast<const f32x4*>(res)[i];
    f32x4 p0 = __builtin_nontemporal_load(reinterpret_cast<const f32x4*>(p) + i);
    f32x4 p1 = __builtin_nontemporal_load(reinterpret_cast<const f32x4*>(p) + i + str4);
    f32x4 o;
    o.x = h.x + p0.x + p1.x; o.y = h.y + p0.y + p1.y;
    o.z = h.z + p0.z + p1.z; o.w = h.w + p0.w + p1.w;
    __builtin_nontemporal_store(o, reinterpret_cast<f32x4*>(out) + i);
  }
}

// ---------------- bf16 transpose: in[S][ldin] (64-col slice) -> out[.][S] ----------------
__global__ void transpose_kernel(const u16* __restrict__ in, u16* __restrict__ out,
                                 int S, int ldin) {
  __shared__ __align__(16) u16 t[64][80];
  int sbT = S >> 6;
  int bs = blockIdx.x % sbT, bc = blockIdx.x / sbT;
  int s0 = bs << 6, c0 = bc << 6;
  int tid = threadIdx.x;
  int ir = tid >> 3;
  int jc = (tid & 7) * 8;
#pragma unroll
  for (int h = 0; h < 2; ++h) {
    int sr = ir + h * 32;
    uint4 v = *reinterpret_cast<const uint4*>(in + (size_t)(s0 + sr) * ldin + c0 + jc);
    *reinterpret_cast<uint4*>(&t[sr][jc]) = v;
  }
  __syncthreads();
  int d = tid >> 3;
  int ss = (tid & 7) * 8;
#pragma unroll
  for (int h = 0; h < 2; ++h) {
    int dd = d + h * 32;
    u16 tmp[8];
#pragma unroll
    for (int e = 0; e < 8; ++e) tmp[e] = t[ss + e][dd];
    *reinterpret_cast<uint4*>(out + (size_t)(c0 + dd) * S + s0 + ss) =
        *reinterpret_cast<const uint4*>(tmp);
  }
}

// ---------------- causal flash attention (QBLK=16, 2 blocks/CU) -------------
// r10/r11: QBLK=16 + balanced pairs (pi, 127-pi) -> grid 512 = 2 blocks/CU,
// lower VGPR -> 2x latency hiding (attn 275 -> out of top-5). Keep this kernel
// single-purpose (r7: co-compiled branches inflate VGPR 84->172, 3x slower).
__global__ __launch_bounds__(256) void attn_kernel(
    const u16* __restrict__ q, const u16* __restrict__ k,
    const u16* __restrict__ vt, u16* __restrict__ o, int S, int ldqk) {
  __shared__ __align__(16) u16 plds[4][16 * 64];
  int tid = threadIdx.x, wid = tid >> 6, lane = tid & 63;
  int lg = lane >> 4, li = lane & 15;
  int nwg = gridDim.x;
  int sbid = (blockIdx.x & 7) * (nwg >> 3) + (blockIdx.x >> 3);
  int task = sbid * 4 + wid;
  int pairs = S >> 5;            // 64 pairs of 16-row tiles (128 tiles/head)
  int head = task / pairs;
  int pi = task - head * pairs;
  const float scale = 0.08838834764831845f;
  u16* pl = plds[wid];
  int ntiles = S >> 4;           // 128

  for (int tix = 0; tix < 2; ++tix) {
    int qt = tix ? (ntiles - 1 - pi) : pi;
    int q0 = qt << 4;

    bf16x8 aq[4];
    {
      const u16* qrow = q + (size_t)(q0 + li) * ldqk + head * HD + lg * 8;
#pragma unroll
      for (int ks = 0; ks < 4; ++ks)
        aq[ks] = *reinterpret_cast<const bf16x8*>(qrow + ks * 32);
    }

    f32x4 oacc[8] = {};
    float m_run[4], l_run[4];
#pragma unroll
    for (int r = 0; r < 4; ++r) { m_run[r] = -INFINITY; l_run[r] = 0.f; }

    int nkb = ((q0 + 15) >> 6) + 1;
    for (int kb = 0; kb < nkb; ++kb) {
      int kvbase = kb << 6;
      f32x4 sacc[4] = {};
#pragma unroll
      for (int cf = 0; cf < 4; ++cf) {
        const u16* krow = k + (size_t)(kvbase + cf * 16 + li) * ldqk + head * HD + lg * 8;
#pragma unroll
        for (int ks = 0; ks < 4; ++ks) {
          bf16x8 bk = *reinterpret_cast<const bf16x8*>(krow + ks * 32);
          sacc[cf] = __builtin_amdgcn_mfma_f32_16x16x32_bf16(aq[ks], bk, sacc[cf], 0, 0, 0);
        }
      }
      bool bnd = (kvbase + 63) > q0;
      float alpha[4];
#pragma unroll
      for (int r = 0; r < 4; ++r) {
        int row = q0 + lg * 4 + r;
#pragma unroll
        for (int cf = 0; cf < 4; ++cf) {
          float sv = sacc[cf][r] * scale;
          if (bnd && (kvbase + cf * 16 + li) > row) sv = -INFINITY;
          sacc[cf][r] = sv;
        }
        float mv = fmaxf(fmaxf(sacc[0][r], sacc[1][r]),
                         fmaxf(sacc[2][r], sacc[3][r]));
#pragma unroll
        for (int off = 1; off < 16; off <<= 1) mv = fmaxf(mv, __shfl_xor(mv, off));
        float mnew = fmaxf(m_run[r], mv);
        alpha[r] = __expf(m_run[r] - mnew);
        m_run[r] = mnew;
        float ps = 0.f;
#pragma unroll
        for (int cf = 0; cf < 4; ++cf) {
          float pv = __expf(sacc[cf][r] - mnew);
          sacc[cf][r] = pv;
          ps += pv;
        }
#pragma unroll
        for (int off = 1; off < 16; off <<= 1) ps += __shfl_xor(ps, off);
        l_run[r] = l_run[r] * alpha[r] + ps;
      }
#pragma unroll
      for (int df = 0; df < 8; ++df)
#pragma unroll
        for (int r = 0; r < 4; ++r) oacc[df][r] *= alpha[r];
      // P -> LDS (16x64 per wave, XOR-swizzled)
#pragma unroll
      for (int cf = 0; cf < 4; ++cf)
#pragma unroll
        for (int r = 0; r < 4; ++r) {
          int row = lg * 4 + r;
          int el = row * 64 + cf * 16 + li;
          pl[el ^ ((row & 7) << 3)] = f32_to_bf16(sacc[cf][r]);
        }
      asm volatile("s_waitcnt lgkmcnt(0)" ::: "memory");
      __builtin_amdgcn_sched_barrier(0);
#pragma unroll
      for (int kk = 0; kk < 2; ++kk) {
        int el = li * 64 + kk * 32 + lg * 8;
        bf16x8 pa = *reinterpret_cast<const bf16x8*>(pl + (el ^ ((li & 7) << 3)));
        const u16* vb = vt + kvbase + kk * 32 + lg * 8;
#pragma unroll
        for (int df = 0; df < 8; ++df) {
          bf16x8 bv = *reinterpret_cast<const bf16x8*>(vb + (size_t)(head * HD + df * 16 + li) * S);
          oacc[df] = __builtin_amdgcn_mfma_f32_16x16x32_bf16(pa, bv, oacc[df], 0, 0, 0);
        }
      }
    }
#pragma unroll
    for (int r = 0; r < 4; ++r) {
      float inv = 1.0f / l_run[r];
      int row = q0 + lg * 4 + r;
      u16* orow = o + (size_t)row * H_DIM + head * HD;
#pragma unroll
      for (int df = 0; df < 8; ++df)
        orow[df * 16 + li] = f32_to_bf16(oacc[df][r] * inv);
    }
  }
}

extern "C" void kernel_launch(void* const* d_in, const int* in_sizes, int n_in,
                              void* d_out, int out_size, void* d_ws, size_t ws_size,
                              hipStream_t stream) {
  (void)n_in; (void)out_size;
  const float* hidden = (const float*)d_in[0];
  const float* wq = (const float*)d_in[2];
  const float* bq = (const float*)d_in[3];
  const float* wk = (const float*)d_in[4];
  const float* bk = (const float*)d_in[5];
  const float* wv = (const float*)d_in[6];
  const float* bv = (const float*)d_in[7];
  const float* wo = (const float*)d_in[8];
  const float* bo = (const float*)d_in[9];
  const float* wg = (const float*)d_in[10];
  const float* wu = (const float*)d_in[11];
  const float* wd = (const float*)d_in[12];
  const float* ln1 = (const float*)d_in[13];
  const float* ln2 = (const float*)d_in[14];
  float* out = (float*)d_out;

  int S = in_sizes[0] / H_DIM;  // 2048
  int NQKV = 3 * H_DIM;         // 12288

  char* ws = (char*)d_ws;
  size_t off = 0;
  auto alloc = [&](size_t bytes) {
    void* p = ws + off;
    off += (bytes + 255) & ~(size_t)255;
    return p;
  };
  u16* wbuf  = (u16*)alloc((size_t)FF_DIM * H_DIM * 2);  // weight buffer A (qkv/wo/wg/wd)
  u16* wbufU = (u16*)alloc((size_t)FF_DIM * H_DIM * 2);  // weight buffer B (wu)
  u16* xb   = (u16*)alloc((size_t)S * H_DIM * 2);
  u16* qkv  = (u16*)alloc((size_t)S * NQKV * 2);        // [S][12288]
  u16* vtb  = (u16*)alloc((size_t)S * H_DIM * 2);       // V^T [4096][S]
  u16* hat  = (u16*)alloc((size_t)S * H_DIM * 2);
  float* h1 = (float*)alloc((size_t)S * H_DIM * 4);
  u16* tb   = (u16*)alloc((size_t)S * FF_DIM * 2);      // silu(gate)*up
  float* bcat = (float*)alloc((size_t)NQKV * 4);
  if (off > ws_size) return;
  // split-K partials overlay qkv+vtb (both dead by O-proj / down-proj time):
  // need 2*S*H*4 = 67.11 MB; qkv(50.33) + vtb(16.78) = 67.11 MB exactly.
  float* pbuf = (float*)qkv;

  dim3 b256(256), b512(512);
  long nHH4 = (long)H_DIM * H_DIM / 4;
  long nFH4 = (long)FF_DIM * H_DIM / 4;
  int gQKV3 = (S / 256) * (NQKV / 256);      // 384
  int gO    = 2 * (S / 256) * (H_DIM / 256); // 256 (split-K=2)
  int gGLU  = (S / 256) * (FF_DIM / 128);    // 896 (fused gate+up, 128-wide)
  int gDW   = 2 * (S / 256) * (H_DIM / 256); // 256 (split-K=2)
  long n4HH = (long)S * H_DIM / 4;
  int gAttn = (NHEAD * (S / 16)) / 2 / 4;    // 512 (2048 pair-tasks / 4 waves)

  // attention block
  rmsnorm_kernel<<<S, b256, 0, stream>>>(hidden, ln1, xb);
  bias_concat_kernel<<<NQKV / 256, b256, 0, stream>>>(bq, bk, bv, bcat);
  f2b3_kernel<<<4096, b256, 0, stream>>>(wq, wk, wv, wbuf, nHH4);
  gemm256<EPI_QKV, false><<<gQKV3, b512, 0, stream>>>(
      xb, wbuf, nullptr, qkv, bcat, nullptr, S, NQKV, H_DIM, H_DIM);
  transpose_kernel<<<(S / 64) * (H_DIM / 64), b256, 0, stream>>>(qkv + 2 * H_DIM, vtb, S, NQKV);
  attn_kernel<<<gAttn, b256, 0, stream>>>(qkv, qkv + H_DIM, vtb, hat, S, NQKV);
  f2b_kernel<<<4096, b256, 0, stream>>>(wo, wbuf, nHH4);
  gemm256<EPI_PART, true><<<gO, b512, 0, stream>>>(
      hat, wbuf, nullptr, pbuf, bo, nullptr, S, H_DIM, H_DIM, H_DIM / 2);
  reduce_down<<<2048, b256, 0, stream>>>(pbuf, hidden, h1, n4HH, n4HH);

  // MLP block (fused gate+up)
  rmsnorm_kernel<<<S, b256, 0, stream>>>(h1, ln2, xb);
  f2b_kernel<<<4096, b256, 0, stream>>>(wg, wbuf, nFH4);
  f2b_kernel<<<4096, b256, 0, stream>>>(wu, wbufU, nFH4);
  gemm256<EPI_GLU, false><<<gGLU, b512, 0, stream>>>(
      xb, wbuf, wbufU, tb, nullptr, nullptr, S, FF_DIM, H_DIM, H_DIM);
  f2b_kernel<<<4096, b256, 0, stream>>>(wd, wbuf, nFH4);
  gemm256<EPI_PART, true><<<gDW, b512, 0, stream>>>(
      tb, wbuf, nullptr, pbuf, nullptr, nullptr, S, H_DIM, FF_DIM, FF_DIM / 2);
  reduce_down<<<2048, b256, 0, stream>>>(pbuf, h1, out, n4HH, n4HH);
}

// Round 15
// 1486.747 us; speedup vs baseline: 1.0055x; 1.0055x over previous
//
#include <hip/hip_runtime.h>
#include <math.h>

#define H_DIM 4096
#define NHEAD 32
#define HD 128
#define FF_DIM 14336

typedef unsigned short u16;
typedef __attribute__((ext_vector_type(8))) short bf16x8;
typedef __attribute__((ext_vector_type(4))) float f32x4;
typedef __attribute__((ext_vector_type(4))) unsigned short u16x4;

typedef const __attribute__((address_space(1))) void* gas_ptr;
typedef __attribute__((address_space(3))) void* las_ptr;

__device__ __forceinline__ void gload_lds16(const void* g, void* l) {
  __builtin_amdgcn_global_load_lds((gas_ptr)g, (las_ptr)l, 16, 0, 0);
}

__device__ __forceinline__ u16 f32_to_bf16(float f) {
  unsigned int u = __float_as_uint(f);
  u = (u + 0x7FFFu + ((u >> 16) & 1u)) >> 16;
  return (u16)u;
}
__device__ __forceinline__ float bf16_to_f32(u16 x) {
  return __uint_as_float(((unsigned int)x) << 16);
}

// read-once fp32 -> bf16 (non-temporal load keeps weight fp32 out of L2 so the
// following GEMM's bf16 panels stay resident — r10: -137us total)
__device__ __forceinline__ void conv4(const float* __restrict__ in,
                                      u16* __restrict__ out, long i) {
  const f32x4* p = reinterpret_cast<const f32x4*>(in) + i;
  f32x4 v = __builtin_nontemporal_load(p);
  u16x4 o;
  o.x = f32_to_bf16(v.x); o.y = f32_to_bf16(v.y);
  o.z = f32_to_bf16(v.z); o.w = f32_to_bf16(v.w);
  reinterpret_cast<u16x4*>(out)[i] = o;
}

// ---------------- fp32 -> bf16 weight conversion ----------------
__global__ void f2b_kernel(const float* __restrict__ in, u16* __restrict__ out, long n4) {
  long i = (long)blockIdx.x * blockDim.x + threadIdx.x;
  long stride = (long)gridDim.x * blockDim.x;
  for (; i < n4; i += stride) conv4(in, out, i);
}

// four equal-size H*H weights -> one contiguous bf16 buffer (wq|wk|wv|wo)
__global__ void f2b4_kernel(const float* __restrict__ a, const float* __restrict__ b,
                            const float* __restrict__ c, const float* __restrict__ d,
                            u16* __restrict__ out, long n4each) {
  long i = (long)blockIdx.x * blockDim.x + threadIdx.x;
  long st = (long)gridDim.x * blockDim.x;
  long tot = 4 * n4each;
  for (; i < tot; i += st) {
    const float* src; long j;
    if (i < n4each)            { src = a; j = i; }
    else if (i < 2 * n4each)   { src = b; j = i - n4each; }
    else if (i < 3 * n4each)   { src = c; j = i - 2 * n4each; }
    else                       { src = d; j = i - 3 * n4each; }
    const f32x4* p = reinterpret_cast<const f32x4*>(src) + j;
    f32x4 v = __builtin_nontemporal_load(p);
    u16x4 o;
    o.x = f32_to_bf16(v.x); o.y = f32_to_bf16(v.y);
    o.z = f32_to_bf16(v.z); o.w = f32_to_bf16(v.w);
    reinterpret_cast<u16x4*>(out)[i] = o;
  }
}

// ---------------- bias concat (fp32) ----------------
__global__ void bias_concat_kernel(const float* __restrict__ a, const float* __restrict__ b,
                                   const float* __restrict__ c, float* __restrict__ out) {
  int i = blockIdx.x * blockDim.x + threadIdx.x;
  float v;
  if (i < 4096) v = a[i];
  else if (i < 8192) v = b[i - 4096];
  else v = c[i - 8192];
  out[i] = v;
}

// ---------------- RMSNorm (fp32 in, bf16 out) ----------------
__global__ void rmsnorm_kernel(const float* __restrict__ in, const float* __restrict__ w,
                               u16* __restrict__ out) {
  int row = blockIdx.x;
  int tid = threadIdx.x;
  const float4* x4 = reinterpret_cast<const float4*>(in + (size_t)row * H_DIM);
  float4 vv[4];
  float ss = 0.f;
#pragma unroll
  for (int it = 0; it < 4; ++it) {
    float4 v = x4[tid + it * 256];
    vv[it] = v;
    ss += v.x * v.x + v.y * v.y + v.z * v.z + v.w * v.w;
  }
#pragma unroll
  for (int off = 1; off < 64; off <<= 1) ss += __shfl_xor(ss, off);
  __shared__ float part[4];
  if ((tid & 63) == 0) part[tid >> 6] = ss;
  __syncthreads();
  float tot = part[0] + part[1] + part[2] + part[3];
  float rinv = rsqrtf(tot * (1.0f / H_DIM) + 1e-6f);
  const float4* w4 = reinterpret_cast<const float4*>(w);
  u16* orow = out + (size_t)row * H_DIM;
#pragma unroll
  for (int it = 0; it < 4; ++it) {
    float4 v = vv[it];
    float4 wv = w4[tid + it * 256];
    ushort4 o;
    o.x = f32_to_bf16(v.x * rinv * wv.x);
    o.y = f32_to_bf16(v.y * rinv * wv.y);
    o.z = f32_to_bf16(v.z * rinv * wv.z);
    o.w = f32_to_bf16(v.w * rinv * wv.w);
    reinterpret_cast<ushort4*>(orow)[tid + it * 256] = o;
  }
}

// ---- fused: h1 = res + p0 + p1 ; xb = rmsnorm(h1)*w (kills h1 HBM re-read) --
__global__ void reduce_rms_kernel(const float* __restrict__ p, const float* __restrict__ res,
                                  const float* __restrict__ w, float* __restrict__ h1,
                                  u16* __restrict__ xb, long str4) {
  int row = blockIdx.x;
  int tid = threadIdx.x;
  long base = (long)row * (H_DIM / 4);
  float4 hv[4];
  float ss = 0.f;
#pragma unroll
  for (int it = 0; it < 4; ++it) {
    long i = base + tid + it * 256;
    f32x4 r  = reinterpret_cast<const f32x4*>(res)[i];
    f32x4 p0 = __builtin_nontemporal_load(reinterpret_cast<const f32x4*>(p) + i);
    f32x4 p1 = __builtin_nontemporal_load(reinterpret_cast<const f32x4*>(p) + i + str4);
    float4 h;
    h.x = r.x + p0.x + p1.x; h.y = r.y + p0.y + p1.y;
    h.z = r.z + p0.z + p1.z; h.w = r.w + p0.w + p1.w;
    hv[it] = h;
    reinterpret_cast<float4*>(h1)[i] = h;
    ss += h.x * h.x + h.y * h.y + h.z * h.z + h.w * h.w;
  }
#pragma unroll
  for (int off = 1; off < 64; off <<= 1) ss += __shfl_xor(ss, off);
  __shared__ float part[4];
  if ((tid & 63) == 0) part[tid >> 6] = ss;
  __syncthreads();
  float tot = part[0] + part[1] + part[2] + part[3];
  float rinv = rsqrtf(tot * (1.0f / H_DIM) + 1e-6f);
  const float4* w4 = reinterpret_cast<const float4*>(w);
  u16* orow = xb + (size_t)row * H_DIM;
#pragma unroll
  for (int it = 0; it < 4; ++it) {
    float4 h = hv[it];
    float4 wv = w4[tid + it * 256];
    ushort4 o;
    o.x = f32_to_bf16(h.x * rinv * wv.x);
    o.y = f32_to_bf16(h.y * rinv * wv.y);
    o.z = f32_to_bf16(h.z * rinv * wv.z);
    o.w = f32_to_bf16(h.w * rinv * wv.w);
    reinterpret_cast<ushort4*>(orow)[tid + it * 256] = o;
  }
}

// ================= 256x256 8-phase bf16 GEMM (T1+T2+T3+T4+T5) =================
// EXACT round-6 proven K-loop (288us FF, MfmaUtil 35.5%, 0 conflicts, VGPR 112).
// EPI_GLU: fused gate+up — block computes 256x128 of BOTH matrices over one
// A-tile (B1 half = wg cols, B2 half = wu cols; identity row map per half);
// epilogue silu(g)*u -> tb (kills 118MB sg round-trip).
// Lessons ledger:
//  r5: unified VGPR budget 256/wave; reg-staged conversion pipelines spill.
//  r8: never co-schedule converter blocks with this kernel (L2 B-panel evict).
//  r9: frag-prefetch hoist NEUTRAL; extra regs only hurt.
//  r10: nt-loads on read-once fp32 streams protect B-panel L2 residency.
//  r14 ceiling model: per-K-tile = MFMA 0.86 + ds_read 0.64 + stage 0.48us +
//  barriers ~= measured 2.23us — barrier-lockstep serializes pipes; fixing it
//  needs 2 blocks/CU (m232: documented-null at 128²+8ph) or asm wave-spec.
enum { EPI_QKV = 0, EPI_O = 1, EPI_SILU = 2, EPI_MUL = 3, EPI_PART = 4, EPI_GLU = 5 };

template <int EPI, bool SPLIT>
__global__ __launch_bounds__(512, 2) void gemm256(
    const u16* __restrict__ A, const u16* __restrict__ B, const u16* __restrict__ Bu,
    void* __restrict__ outp, const float* __restrict__ bias, const void* __restrict__ extra,
    int M, int N, int K, int kLen) {
  __shared__ __align__(16) u16 As[2][256 * 64];
  __shared__ __align__(16) u16 Bs[2][256 * 64];
  const int tid = threadIdx.x;
  const int wid = tid >> 6, lane = tid & 63;
  const int lg = lane >> 4, li = lane & 15;
  const int wr = (wid >> 2) << 7;  // 0 / 128
  const int wc = (wid & 3) << 6;   // 0,64,128,192 (256-wide tiles)
  const int wcg = (wid & 3) << 5;  // 0,32,64,96  (GLU: 128-wide per matrix)

  const int nbm = M >> 8;
  const int nbn = (EPI == EPI_GLU) ? (N >> 7) : (N >> 8);
  const int nb = nbm * nbn;
  int wg = (blockIdx.x & 7) * (gridDim.x >> 3) + (blockIdx.x >> 3);
  int s = 0;
  if (SPLIT) { s = wg / nb; wg -= s * nb; }
  const int m0 = (wg % nbm) << 8;
  const int n0 = (EPI == EPI_GLU) ? ((wg / nbm) << 7) : ((wg / nbm) << 8);
  const int kB = SPLIT ? s * kLen : 0;
  const int NT = kLen >> 6;

  // staging source pointers (pre-inverse-swizzled) + LDS dest offsets
  const int r8 = tid >> 3;
  const int sl = ((tid & 7) ^ (r8 & 7)) << 3;
  const u16* sA[2][2];
  const u16* sB[2][2];
  int ldo[2][2];
#pragma unroll
  for (int P = 0; P < 2; ++P)
#pragma unroll
    for (int h = 0; h < 2; ++h) {
      int lr = P * 128 + h * 64 + r8;
      int ra = (lr & 63) | ((lr >> 1) & 64) | ((lr << 1) & 128);
      sA[P][h] = A + (size_t)(m0 + ra) * K + kB + sl;
      if (EPI == EPI_GLU) {
        const u16* srcm = P ? Bu : B;              // B1 half = wg, B2 half = wu
        sB[P][h] = srcm + (size_t)(n0 + h * 64 + r8) * K + sl;
      } else {
        int rb = (lr & 31) | ((lr & 96) << 1) | ((lr & 128) >> 2);
        sB[P][h] = B + (size_t)(n0 + rb) * K + kB + sl;
      }
      ldo[P][h] = (P * 128 + h * 64 + (wid << 3)) << 6;
    }

  auto stageA = [&](int P, int d, int ko) {
#pragma unroll
    for (int h = 0; h < 2; ++h)
      gload_lds16(sA[P][h] + ko, (void*)(&As[d][ldo[P][h]]));
  };
  auto stageB = [&](int P, int d, int ko) {
#pragma unroll
    for (int h = 0; h < 2; ++h)
      gload_lds16(sB[P][h] + ko, (void*)(&Bs[d][ldo[P][h]]));
  };

  bf16x8 a[4][2], b[4][2];
  f32x4 acc[8][4] = {};
  const int s20 = (lg ^ (li & 7)) << 3;
  const int s21 = ((4 + lg) ^ (li & 7)) << 3;

  auto ldA = [&](int d, int set) {
#pragma unroll
    for (int i = 0; i < 4; ++i) {
      int g = wr + set * 64 + i * 16;
      int lb = (g & 63) | ((g >> 1) & 64) | ((g << 1) & 128);
      const u16* base = &As[d][(lb + li) << 6];
      a[i][0] = *reinterpret_cast<const bf16x8*>(base + s20);
      a[i][1] = *reinterpret_cast<const bf16x8*>(base + s21);
    }
  };
  auto ldB = [&](int d, int set) {
#pragma unroll
    for (int jj = 0; jj < 2; ++jj) {
      int lb;
      if (EPI == EPI_GLU) {
        lb = set * 128 + wcg + jj * 16;            // identity map within half
      } else {
        int hh = wc + (set * 2 + jj) * 16;
        lb = ((hh & 32) << 2) | ((hh & 192) >> 1) | (hh & 31);
      }
      const u16* base = &Bs[d][(lb + li) << 6];
      b[set * 2 + jj][0] = *reinterpret_cast<const bf16x8*>(base + s20);
      b[set * 2 + jj][1] = *reinterpret_cast<const bf16x8*>(base + s21);
    }
  };
  auto mm = [&](int iset, int jset) {
    __builtin_amdgcn_s_setprio(1);
#pragma unroll
    for (int i = 0; i < 4; ++i)
#pragma unroll
      for (int jj = 0; jj < 2; ++jj)
#pragma unroll
        for (int kk = 0; kk < 2; ++kk)
          acc[iset * 4 + i][jset * 2 + jj] = __builtin_amdgcn_mfma_f32_16x16x32_bf16(
              a[i][kk], b[jset * 2 + jj][kk], acc[iset * 4 + i][jset * 2 + jj], 0, 0, 0);
    __builtin_amdgcn_s_setprio(0);
  };

  // prologue: stage tiles 0 and 1
  stageA(0, 0, 0); stageB(0, 0, 0); stageB(1, 0, 0); stageA(1, 0, 0);
  if (NT > 1) {
    stageA(0, 1, 64); stageB(0, 1, 64); stageB(1, 1, 64); stageA(1, 1, 64);
    asm volatile("s_waitcnt vmcnt(8)" ::: "memory");
  } else {
    asm volatile("s_waitcnt vmcnt(0)" ::: "memory");
  }
  __builtin_amdgcn_s_barrier();

  for (int t = 0; t < NT; ++t) {
    int d = t & 1;
    bool pf = (t + 2) < NT;
    int ko = (t + 2) << 6;
    // ---- phase 1: reads A1+B1; MFMA quadrant (i0-3, j0-1)
    ldB(d, 0); ldA(d, 0);
    __builtin_amdgcn_s_barrier();
    mm(0, 0);
    __builtin_amdgcn_s_barrier();
    // ---- phase 2: reads B2; stage t+2.{A1,B1}; MFMA (i0-3, j2-3)
    ldB(d, 1);
    if (pf) { stageA(0, d, ko); stageB(0, d, ko); }
    __builtin_amdgcn_s_barrier();
    mm(0, 1);
    __builtin_amdgcn_s_barrier();
    // ---- phase 3: reads A2; stage t+2.B2; MFMA (i4-7, j0-1)
    ldA(d, 1);
    if (pf) stageB(1, d, ko);
    __builtin_amdgcn_s_barrier();
    mm(1, 0);
    __builtin_amdgcn_s_barrier();
    // ---- phase 4: stage t+2.A2; counted vmcnt; MFMA (i4-7, j2-3)
    if (pf) {
      stageA(1, d, ko);
      asm volatile("s_waitcnt vmcnt(6)" ::: "memory");
    } else {
      asm volatile("s_waitcnt vmcnt(0)" ::: "memory");
    }
    __builtin_amdgcn_s_barrier();
    mm(1, 1);
    __builtin_amdgcn_s_barrier();
  }

  // ---- epilogue
  if (EPI == EPI_GLU) {
#pragma unroll
    for (int i = 0; i < 8; ++i) {
#pragma unroll
      for (int jj = 0; jj < 2; ++jj) {
        int col = n0 + wcg + jj * 16 + li;
#pragma unroll
        for (int r = 0; r < 4; ++r) {
          int row = m0 + wr + i * 16 + lg * 4 + r;
          float g = acc[i][jj][r];
          float u = acc[i][2 + jj][r];
          float sv = (g / (1.f + __expf(-g))) * u;
          ((u16*)outp)[(size_t)row * N + col] = f32_to_bf16(sv);
        }
      }
    }
    return;
  }
#pragma unroll
  for (int i = 0; i < 8; ++i) {
#pragma unroll
    for (int j = 0; j < 4; ++j) {
      int col = n0 + wc + j * 16 + li;
      float bv = 0.f;
      if (EPI == EPI_QKV || EPI == EPI_O) bv = bias[col];
      if (EPI == EPI_PART && bias != nullptr && s == 0) bv = bias[col];
#pragma unroll
      for (int r = 0; r < 4; ++r) {
        int row = m0 + wr + i * 16 + lg * 4 + r;
        float v = acc[i][j][r] + bv;
        size_t idx = (size_t)row * N + col;
        if (EPI == EPI_QKV) {
          ((u16*)outp)[idx] = f32_to_bf16(v);
        } else if (EPI == EPI_O) {
          const float* res = (const float*)extra;
          ((float*)outp)[idx] = res[idx] + v;
        } else if (EPI == EPI_SILU) {
          float sv = v / (1.f + __expf(-v));
          ((u16*)outp)[idx] = f32_to_bf16(sv);
        } else if (EPI == EPI_MUL) {
          const u16* sg = (const u16*)extra;
          ((u16*)outp)[idx] = f32_to_bf16(v * bf16_to_f32(sg[idx]));
        } else {  // EPI_PART: split-K partial, plain fp32 (bias folded at s==0)
          ((float*)outp)[(size_t)s * M * N + idx] = v;
        }
      }
    }
  }
}

// ---------------- split-K reduce + residual: out = res + p0 + p1 ----------------
__global__ void reduce_down(const float* __restrict__ p, const float* __restrict__ res,
                            float* __restrict__ out, long n4, long str4) {
  long i = (long)blockIdx.x * blockDim.x + threadIdx.x;
  long st = (long)gridDim.x * blockDim.x;
  for (; i < n4; i += st) {
    f32x4 h = reinterpret_cast<const f32x4*>(res)[i];
    f32x4 p0 = __builtin_nontemporal_load(reinterpret_cast<const f32x4*>(p) + i);
    f32x4 p1 = __builtin_nontemporal_load(reinterpret_cast<const f32x4*>(p) + i + str4);
    f32x4 o;
    o.x = h.x + p0.x + p1.x; o.y = h.y + p0.y + p1.y;
    o.z = h.z + p0.z + p1.z; o.w = h.w + p0.w + p1.w;
    __builtin_nontemporal_store(o, reinterpret_cast<f32x4*>(out) + i);
  }
}

// ---------------- bf16 transpose: in[S][ldin] (64-col slice) -> out[.][S] ----------------
__global__ void transpose_kernel(const u16* __restrict__ in, u16* __restrict__ out,
                                 int S, int ldin) {
  __shared__ __align__(16) u16 t[64][80];
  int sbT = S >> 6;
  int bs = blockIdx.x % sbT, bc = blockIdx.x / sbT;
  int s0 = bs << 6, c0 = bc << 6;
  int tid = threadIdx.x;
  int ir = tid >> 3;
  int jc = (tid & 7) * 8;
#pragma unroll
  for (int h = 0; h < 2; ++h) {
    int sr = ir + h * 32;
    uint4 v = *reinterpret_cast<const uint4*>(in + (size_t)(s0 + sr) * ldin + c0 + jc);
    *reinterpret_cast<uint4*>(&t[sr][jc]) = v;
  }
  __syncthreads();
  int d = tid >> 3;
  int ss = (tid & 7) * 8;
#pragma unroll
  for (int h = 0; h < 2; ++h) {
    int dd = d + h * 32;
    u16 tmp[8];
#pragma unroll
    for (int e = 0; e < 8; ++e) tmp[e] = t[ss + e][dd];
    *reinterpret_cast<uint4*>(out + (size_t)(c0 + dd) * S + s0 + ss) =
        *reinterpret_cast<const uint4*>(tmp);
  }
}

// ---------------- causal flash attention (QBLK=16, 2 blocks/CU) -------------
// r10/r11: QBLK=16 + balanced pairs (pi, 127-pi) -> grid 512 = 2 blocks/CU,
// lower VGPR -> 2x latency hiding (attn 275 -> ~130us). Keep this kernel
// single-purpose (r7: co-compiled branches inflate VGPR 84->172, 3x slower).
__global__ __launch_bounds__(256) void attn_kernel(
    const u16* __restrict__ q, const u16* __restrict__ k,
    const u16* __restrict__ vt, u16* __restrict__ o, int S, int ldqk) {
  __shared__ __align__(16) u16 plds[4][16 * 64];
  int tid = threadIdx.x, wid = tid >> 6, lane = tid & 63;
  int lg = lane >> 4, li = lane & 15;
  int nwg = gridDim.x;
  int sbid = (blockIdx.x & 7) * (nwg >> 3) + (blockIdx.x >> 3);
  int task = sbid * 4 + wid;
  int pairs = S >> 5;            // 64 pairs of 16-row tiles (128 tiles/head)
  int head = task / pairs;
  int pi = task - head * pairs;
  const float scale = 0.08838834764831845f;
  u16* pl = plds[wid];
  int ntiles = S >> 4;           // 128

  for (int tix = 0; tix < 2; ++tix) {
    int qt = tix ? (ntiles - 1 - pi) : pi;
    int q0 = qt << 4;

    bf16x8 aq[4];
    {
      const u16* qrow = q + (size_t)(q0 + li) * ldqk + head * HD + lg * 8;
#pragma unroll
      for (int ks = 0; ks < 4; ++ks)
        aq[ks] = *reinterpret_cast<const bf16x8*>(qrow + ks * 32);
    }

    f32x4 oacc[8] = {};
    float m_run[4], l_run[4];
#pragma unroll
    for (int r = 0; r < 4; ++r) { m_run[r] = -INFINITY; l_run[r] = 0.f; }

    int nkb = ((q0 + 15) >> 6) + 1;
    for (int kb = 0; kb < nkb; ++kb) {
      int kvbase = kb << 6;
      f32x4 sacc[4] = {};
#pragma unroll
      for (int cf = 0; cf < 4; ++cf) {
        const u16* krow = k + (size_t)(kvbase + cf * 16 + li) * ldqk + head * HD + lg * 8;
#pragma unroll
        for (int ks = 0; ks < 4; ++ks) {
          bf16x8 bk = *reinterpret_cast<const bf16x8*>(krow + ks * 32);
          sacc[cf] = __builtin_amdgcn_mfma_f32_16x16x32_bf16(aq[ks], bk, sacc[cf], 0, 0, 0);
        }
      }
      bool bnd = (kvbase + 63) > q0;
      float alpha[4];
#pragma unroll
      for (int r = 0; r < 4; ++r) {
        int row = q0 + lg * 4 + r;
#pragma unroll
        for (int cf = 0; cf < 4; ++cf) {
          float sv = sacc[cf][r] * scale;
          if (bnd && (kvbase + cf * 16 + li) > row) sv = -INFINITY;
          sacc[cf][r] = sv;
        }
        float mv = fmaxf(fmaxf(sacc[0][r], sacc[1][r]),
                         fmaxf(sacc[2][r], sacc[3][r]));
#pragma unroll
        for (int off = 1; off < 16; off <<= 1) mv = fmaxf(mv, __shfl_xor(mv, off));
        float mnew = fmaxf(m_run[r], mv);
        alpha[r] = __expf(m_run[r] - mnew);
        m_run[r] = mnew;
        float ps = 0.f;
#pragma unroll
        for (int cf = 0; cf < 4; ++cf) {
          float pv = __expf(sacc[cf][r] - mnew);
          sacc[cf][r] = pv;
          ps += pv;
        }
#pragma unroll
        for (int off = 1; off < 16; off <<= 1) ps += __shfl_xor(ps, off);
        l_run[r] = l_run[r] * alpha[r] + ps;
      }
#pragma unroll
      for (int df = 0; df < 8; ++df)
#pragma unroll
        for (int r = 0; r < 4; ++r) oacc[df][r] *= alpha[r];
      // P -> LDS (16x64 per wave, XOR-swizzled)
#pragma unroll
      for (int cf = 0; cf < 4; ++cf)
#pragma unroll
        for (int r = 0; r < 4; ++r) {
          int row = lg * 4 + r;
          int el = row * 64 + cf * 16 + li;
          pl[el ^ ((row & 7) << 3)] = f32_to_bf16(sacc[cf][r]);
        }
      asm volatile("s_waitcnt lgkmcnt(0)" ::: "memory");
      __builtin_amdgcn_sched_barrier(0);
#pragma unroll
      for (int kk = 0; kk < 2; ++kk) {
        int el = li * 64 + kk * 32 + lg * 8;
        bf16x8 pa = *reinterpret_cast<const bf16x8*>(pl + (el ^ ((li & 7) << 3)));
        const u16* vb = vt + kvbase + kk * 32 + lg * 8;
#pragma unroll
        for (int df = 0; df < 8; ++df) {
          bf16x8 bv = *reinterpret_cast<const bf16x8*>(vb + (size_t)(head * HD + df * 16 + li) * S);
          oacc[df] = __builtin_amdgcn_mfma_f32_16x16x32_bf16(pa, bv, oacc[df], 0, 0, 0);
        }
      }
    }
#pragma unroll
    for (int r = 0; r < 4; ++r) {
      float inv = 1.0f / l_run[r];
      int row = q0 + lg * 4 + r;
      u16* orow = o + (size_t)row * H_DIM + head * HD;
#pragma unroll
      for (int df = 0; df < 8; ++df)
        orow[df * 16 + li] = f32_to_bf16(oacc[df][r] * inv);
    }
  }
}

extern "C" void kernel_launch(void* const* d_in, const int* in_sizes, int n_in,
                              void* d_out, int out_size, void* d_ws, size_t ws_size,
                              hipStream_t stream) {
  (void)n_in; (void)out_size;
  const float* hidden = (const float*)d_in[0];
  const float* wq = (const float*)d_in[2];
  const float* bq = (const float*)d_in[3];
  const float* wk = (const float*)d_in[4];
  const float* bk = (const float*)d_in[5];
  const float* wv = (const float*)d_in[6];
  const float* bv = (const float*)d_in[7];
  const float* wo = (const float*)d_in[8];
  const float* bo = (const float*)d_in[9];
  const float* wg = (const float*)d_in[10];
  const float* wu = (const float*)d_in[11];
  const float* wd = (const float*)d_in[12];
  const float* ln1 = (const float*)d_in[13];
  const float* ln2 = (const float*)d_in[14];
  float* out = (float*)d_out;

  int S = in_sizes[0] / H_DIM;  // 2048
  int NQKV = 3 * H_DIM;         // 12288

  char* ws = (char*)d_ws;
  size_t off = 0;
  auto alloc = [&](size_t bytes) {
    void* p = ws + off;
    off += (bytes + 255) & ~(size_t)255;
    return p;
  };
  // weight buffer A: holds wq|wk|wv|wo (4*H*H = 134MB), later reused for wg/wd
  size_t wbufElems = (size_t)4 * H_DIM * H_DIM;  // >= FF*H (117MB)
  u16* wbuf  = (u16*)alloc(wbufElems * 2);
  u16* wbufU = (u16*)alloc((size_t)FF_DIM * H_DIM * 2);  // weight buffer B (wu)
  u16* xb   = (u16*)alloc((size_t)S * H_DIM * 2);
  u16* qkv  = (u16*)alloc((size_t)S * NQKV * 2);        // [S][12288]
  u16* vtb  = (u16*)alloc((size_t)S * H_DIM * 2);       // V^T [4096][S]
  u16* hat  = (u16*)alloc((size_t)S * H_DIM * 2);
  float* h1 = (float*)alloc((size_t)S * H_DIM * 4);
  u16* tb   = (u16*)alloc((size_t)S * FF_DIM * 2);      // silu(gate)*up
  float* bcat = (float*)alloc((size_t)NQKV * 4);
  if (off > ws_size) return;
  // split-K partials overlay qkv+vtb (both dead by O-proj / down-proj time):
  // need 2*S*H*4 = 67.11 MB; qkv(50.33) + vtb(16.78) = 67.11 MB exactly.
  float* pbuf = (float*)qkv;

  dim3 b256(256), b512(512);
  long nHH4 = (long)H_DIM * H_DIM / 4;
  long nFH4 = (long)FF_DIM * H_DIM / 4;
  int gQKV3 = (S / 256) * (NQKV / 256);      // 384
  int gO    = 2 * (S / 256) * (H_DIM / 256); // 256 (split-K=2)
  int gGLU  = (S / 256) * (FF_DIM / 128);    // 896 (fused gate+up, 128-wide)
  int gDW   = 2 * (S / 256) * (H_DIM / 256); // 256 (split-K=2)
  long n4HH = (long)S * H_DIM / 4;
  int gAttn = (NHEAD * (S / 16)) / 2 / 4;    // 512 (2048 pair-tasks / 4 waves)

  // attention block
  rmsnorm_kernel<<<S, b256, 0, stream>>>(hidden, ln1, xb);
  bias_concat_kernel<<<NQKV / 256, b256, 0, stream>>>(bq, bk, bv, bcat);
  f2b4_kernel<<<4096, b256, 0, stream>>>(wq, wk, wv, wo, wbuf, nHH4);
  gemm256<EPI_QKV, false><<<gQKV3, b512, 0, stream>>>(
      xb, wbuf, nullptr, qkv, bcat, nullptr, S, NQKV, H_DIM, H_DIM);
  transpose_kernel<<<(S / 64) * (H_DIM / 64), b256, 0, stream>>>(qkv + 2 * H_DIM, vtb, S, NQKV);
  attn_kernel<<<gAttn, b256, 0, stream>>>(qkv, qkv + H_DIM, vtb, hat, S, NQKV);
  // O-proj: B = wo slice of wbuf (offset 3*H*H), split-K=2, bias folded at s=0
  gemm256<EPI_PART, true><<<gO, b512, 0, stream>>>(
      hat, wbuf + (size_t)3 * H_DIM * H_DIM, nullptr, pbuf, bo, nullptr,
      S, H_DIM, H_DIM, H_DIM / 2);
  // fused: h1 = hidden + p0 + p1 ; xb = rmsnorm(h1) * ln2
  reduce_rms_kernel<<<S, b256, 0, stream>>>(pbuf, hidden, ln2, h1, xb, n4HH);

  // MLP block (fused gate+up)
  f2b_kernel<<<4096, b256, 0, stream>>>(wg, wbuf, nFH4);
  f2b_kernel<<<4096, b256, 0, stream>>>(wu, wbufU, nFH4);
  gemm256<EPI_GLU, false><<<gGLU, b512, 0, stream>>>(
      xb, wbuf, wbufU, tb, nullptr, nullptr, S, FF_DIM, H_DIM, H_DIM);
  f2b_kernel<<<4096, b256, 0, stream>>>(wd, wbuf, nFH4);
  gemm256<EPI_PART, true><<<gDW, b512, 0, stream>>>(
      tb, wbuf, nullptr, pbuf, nullptr, nullptr, S, H_DIM, FF_DIM, FF_DIM / 2);
  reduce_down<<<2048, b256, 0, stream>>>(pbuf, h1, out, n4HH, n4HH);
}